// Round 5
// baseline (421.287 us; speedup 1.0000x reference)
//
#include <hip/hip_runtime.h>
#include <hip/hip_bf16.h>

// Problem constants
#define BB 256          // batch
#define FF 128          // features
#define CC 100          // classes
#define KG 512          // split-K groups (blocks of main_gemm)
#define ITPB 16         // it-pairs per main_gemm block (KG*ITPB = 8192)
#define NIT 8192        // total (layer,tree) pairs
#define WT_IT 7168      // ushorts per swizzled it-tile (112 c x 64 l)

typedef short bf16x8 __attribute__((ext_vector_type(8)));
typedef float f32x4 __attribute__((ext_vector_type(4)));
typedef _Float16 f16x8 __attribute__((ext_vector_type(8)));

static __device__ inline unsigned short f2bf(float f) {
    unsigned u = __float_as_uint(f);
    u += 0x7fffu + ((u >> 16) & 1u);   // RNE
    return (unsigned short)(u >> 16);
}
static __device__ inline float bf2f(unsigned short h) {
    return __uint_as_float(((unsigned)h) << 16);
}
// packed f32x2 -> bf16x2 (RNE), low16 = a
static __device__ inline unsigned pk2(float a, float b) {
    __hip_bfloat162 h = __float22bfloat162_rn(float2{a, b});
    union { __hip_bfloat162 h2; unsigned u; } cv; cv.h2 = h;
    return cv.u;
}

// ---------------------------------------------------------------------------
// Kernel 1: fv[row][b] = sigmoid(x[b,:] . sel_W[row,:] + sel_b[row])  (bf16)
// row = it*6 + d  ->  fv[row*256 + b]
// ---------------------------------------------------------------------------
__global__ __launch_bounds__(256) void fv_kernel(
    const float* __restrict__ x, const float* __restrict__ selW,
    const float* __restrict__ selb, unsigned short* __restrict__ fvout)
{
    __shared__ unsigned short wt[128 * 136];
    __shared__ unsigned short xt[128 * 136];
    __shared__ float sb[128];

    const int tid = threadIdx.x;
    const int m0 = blockIdx.x * 128;
    const int n0 = blockIdx.y * 128;

    #pragma unroll 4
    for (int pass = 0; pass < 16; ++pass) {
        int idx = pass * 256 + tid;
        int r = idx >> 5, f4 = idx & 31;
        float4 v = *((const float4*)(selW + (size_t)(m0 + r) * FF) + f4);
        float4 vx = *((const float4*)(x + (size_t)(n0 + r) * FF) + f4);
        ushort4 h;
        h.x = f2bf(v.x); h.y = f2bf(v.y); h.z = f2bf(v.z); h.w = f2bf(v.w);
        *(ushort4*)(wt + r * 136 + f4 * 4) = h;
        ushort4 hx;
        hx.x = f2bf(vx.x); hx.y = f2bf(vx.y); hx.z = f2bf(vx.z); hx.w = f2bf(vx.w);
        *(ushort4*)(xt + r * 136 + f4 * 4) = hx;
    }
    if (tid < 128) sb[tid] = selb[m0 + tid];
    __syncthreads();

    const int w = tid >> 6, lane = tid & 63;
    const int q = lane >> 4, l15 = lane & 15;
    const int mq = w & 1, nq = w >> 1;

    f32x4 zero4 = {0.f, 0.f, 0.f, 0.f};
    f32x4 acc[4][4];
    #pragma unroll
    for (int i = 0; i < 4; ++i)
        #pragma unroll
        for (int j = 0; j < 4; ++j) acc[i][j] = zero4;

    #pragma unroll
    for (int ch = 0; ch < 4; ++ch) {
        bf16x8 a[4];
        #pragma unroll
        for (int ms = 0; ms < 4; ++ms)
            a[ms] = *(const bf16x8*)(wt + (mq * 64 + ms * 16 + l15) * 136 + ch * 32 + q * 8);
        #pragma unroll
        for (int ns = 0; ns < 4; ++ns) {
            bf16x8 bfr = *(const bf16x8*)(xt + (nq * 64 + ns * 16 + l15) * 136 + ch * 32 + q * 8);
            #pragma unroll
            for (int ms = 0; ms < 4; ++ms)
                acc[ms][ns] = __builtin_amdgcn_mfma_f32_16x16x32_bf16(a[ms], bfr, acc[ms][ns], 0, 0, 0);
        }
    }

    #pragma unroll
    for (int ms = 0; ms < 4; ++ms) {
        int rowl = mq * 64 + ms * 16 + q * 4;
        #pragma unroll
        for (int ns = 0; ns < 4; ++ns) {
            int b = n0 + nq * 64 + ns * 16 + l15;
            #pragma unroll
            for (int reg = 0; reg < 4; ++reg) {
                int row = m0 + rowl + reg;
                float z = acc[ms][ns][reg] + sb[rowl + reg];
                float p = 1.0f / (1.0f + __expf(-z));
                fvout[(size_t)row * 256 + b] = f2bf(p);
            }
        }
    }
}

// ---------------------------------------------------------------------------
// Kernel T: outW fp32 [c][it*64+l] -> Wt bf16 [it][B-fragment-swizzled]
// Slot for (c, k): ((ch*4+q)*112 + c)*8 + j  with ch=k>>5, q=(k>>3)&3, j=k&7.
// One block per it; reads 100 x 256 B (contiguous rows), writes 14336 B linear.
// ---------------------------------------------------------------------------
__global__ __launch_bounds__(256) void wt_kernel(
    const float* __restrict__ outW, unsigned short* __restrict__ Wt)
{
    __shared__ unsigned short tile[WT_IT];   // 14336 B
    const int tid = threadIdx.x;
    const int it = blockIdx.x;

    // zero (covers c >= 100 padding)
    #pragma unroll
    for (int i = 0; i < 4; ++i) {
        int s = i * 256 + tid;
        if (s < 896) *(uint4*)(tile + s * 8) = make_uint4(0, 0, 0, 0);
    }
    __syncthreads();

    const int cr = tid >> 4;          // row-group within pass
    const int f4 = tid & 15;          // float4 index within 64-float row
    const int ch4 = (f4 >> 3) * 4 + ((f4 >> 1) & 3);  // ch*4+q for k=f4*4
    const int j0 = (f4 & 1) * 4;

    float4 v[7];
    #pragma unroll
    for (int pass = 0; pass < 7; ++pass) {
        const int c = pass * 16 + cr;
        v[pass] = make_float4(0.f, 0.f, 0.f, 0.f);
        if (c < CC)
            v[pass] = *((const float4*)(outW + (size_t)c * 524288 + (size_t)it * 64) + f4);
    }
    #pragma unroll
    for (int pass = 0; pass < 7; ++pass) {
        const int c = pass * 16 + cr;
        if (c < CC) {
            unsigned lo = pk2(v[pass].x, v[pass].y);
            unsigned hi = pk2(v[pass].z, v[pass].w);
            *(uint2*)(tile + (ch4 * 112 + c) * 8 + j0) = make_uint2(lo, hi);
        }
    }
    __syncthreads();

    uint4* dst = (uint4*)(Wt + (size_t)it * WT_IT);
    const uint4* src = (const uint4*)tile;
    #pragma unroll
    for (int i = 0; i < 4; ++i) {
        int s = i * 256 + tid;
        if (s < 896) dst[s] = src[s];
    }
}

// ---------------------------------------------------------------------------
// Kernel 2: split-K GEMM, NO LDS, NO barriers. Waves fully independent.
// B-frags: direct 16-B coalesced loads from swizzled Wt (4-wave redundancy
// served by L1). A-frags: built in-register from the wave's own 64 lanes of
// probabilities via __shfl (tree-factorized leaf products).
// ---------------------------------------------------------------------------
__global__ __launch_bounds__(256, 2) void main_gemm(
    const unsigned short* __restrict__ fv, const unsigned short* __restrict__ Wt,
    _Float16* __restrict__ part16)
{
    const int tid = threadIdx.x;
    const int kg = blockIdx.x;
    const int w = tid >> 6, lane = tid & 63;
    const int q = lane >> 4, l15 = lane & 15;
    const int qh = q >> 1, ql = q & 1;

    f32x4 zero4 = {0.f, 0.f, 0.f, 0.f};
    f32x4 acc[4][7];
    #pragma unroll
    for (int i = 0; i < 4; ++i)
        #pragma unroll
        for (int j = 0; j < 7; ++j) acc[i][j] = zero4;

    // pv prefetch (distance 1). Lane's own b = tid.
    unsigned short pvb[2][6];
    {
        const unsigned short* fp = fv + (size_t)(kg * ITPB) * 1536 + tid;
        #pragma unroll
        for (int d = 0; d < 6; ++d) pvb[0][d] = fp[d * 256];
    }

    for (int itl = 0; itl < ITPB; ++itl) {
        const int it = kg * ITPB + itl;
        const int cur = itl & 1;

        // prefetch next iteration's probabilities
        if (itl + 1 < ITPB) {
            const unsigned short* fp = fv + (size_t)(it + 1) * 1536 + tid;
            #pragma unroll
            for (int d = 0; d < 6; ++d) pvb[cur ^ 1][d] = fp[d * 256];
        }

        // ---- issue all 14 B-fragment loads (independent; L1-shared) ----
        const unsigned short* wbase = Wt + (size_t)it * WT_IT;
        bf16x8 bfr[2][7];
        #pragma unroll
        for (int ch = 0; ch < 2; ++ch)
            #pragma unroll
            for (int nt = 0; nt < 7; ++nt)
                bfr[ch][nt] = *(const bf16x8*)(wbase + ((ch * 4 + q) * 112 + nt * 16 + l15) * 8);

        // ---- build A-fragments in-register (covers the load latency) ----
        float p[6];
        #pragma unroll
        for (int d = 0; d < 6; ++d) p[d] = bf2f(pvb[cur][d]);

        bf16x8 afr[4][2];
        #pragma unroll
        for (int ms = 0; ms < 4; ++ms) {
            const int src = ms * 16 + l15;
            float s0 = __shfl(p[0], src, 64);
            float s1 = __shfl(p[1], src, 64);
            float s2 = __shfl(p[2], src, 64);
            float s3 = __shfl(p[3], src, 64);
            float s4 = __shfl(p[4], src, 64);
            float s5 = __shfl(p[5], src, 64);
            // leaf l = ch*32 + q*8 + j ; pair-index l>>4 = ch*2+qh ; m = l&15 = ql*8+j
            float t1 = qh ? (1.f - s1) : s1;
            float A0 = s0 * t1;             // ch = 0
            float A1 = (1.f - s0) * t1;     // ch = 1
            float t2 = ql ? (1.f - s2) : s2;
            float Bv0 = t2 * s3;            // j>>2 = 0
            float Bv1 = t2 * (1.f - s3);    // j>>2 = 1
            float n4 = 1.f - s4, n5 = 1.f - s5;
            float Cv0 = s4 * s5, Cv1 = s4 * n5, Cv2 = n4 * s5, Cv3 = n4 * n5;
            #pragma unroll
            for (int ch = 0; ch < 2; ++ch) {
                float A = ch ? A1 : A0;
                float ab0 = A * Bv0, ab1 = A * Bv1;
                union { bf16x8 v; unsigned u[4]; } bu;
                bu.u[0] = pk2(ab0 * Cv0, ab0 * Cv1);
                bu.u[1] = pk2(ab0 * Cv2, ab0 * Cv3);
                bu.u[2] = pk2(ab1 * Cv0, ab1 * Cv1);
                bu.u[3] = pk2(ab1 * Cv2, ab1 * Cv3);
                afr[ms][ch] = bu.v;
            }
        }

        // ---- MFMA ----
        #pragma unroll
        for (int ch = 0; ch < 2; ++ch)
            #pragma unroll
            for (int nt = 0; nt < 7; ++nt)
                #pragma unroll
                for (int ms = 0; ms < 4; ++ms)
                    acc[ms][nt] = __builtin_amdgcn_mfma_f32_16x16x32_bf16(
                        afr[ms][ch], bfr[ch][nt], acc[ms][nt], 0, 0, 0);
    }

    // epilogue: fp16 partials part16[b][kg][c]
    #pragma unroll
    for (int ms = 0; ms < 4; ++ms) {
        const int brow = w * 64 + ms * 16 + q * 4;
        #pragma unroll
        for (int nt = 0; nt < 7; ++nt) {
            const int c = nt * 16 + l15;
            #pragma unroll
            for (int reg = 0; reg < 4; ++reg)
                part16[((size_t)(brow + reg) * KG + kg) * 112 + c] =
                    (_Float16)acc[ms][nt][reg];
        }
    }
}

// ---------------------------------------------------------------------------
// Kernel 3: out[b][c] = sum_kg part16[b][kg][c] + out_b[c]
// One block per b; slice = 512*112 halves = 114688 B contiguous.
// ---------------------------------------------------------------------------
__global__ __launch_bounds__(256) void reduce_k(
    const _Float16* __restrict__ part16, const float* __restrict__ outb,
    float* __restrict__ out)
{
    __shared__ float red[16 * 112];
    const int b = blockIdx.x;
    const int tid = threadIdx.x;
    const f16x8* slice = (const f16x8*)(part16 + (size_t)b * (KG * 112));

    if (tid < 224) {
        const int c8 = tid % 14;       // c base = c8*8
        const int kgs = tid / 14;      // 0..15
        float s[8];
        #pragma unroll
        for (int j = 0; j < 8; ++j) s[j] = 0.f;
        #pragma unroll 4
        for (int i = 0; i < 32; ++i) { // kg = i*16 + kgs
            f16x8 v = slice[i * 224 + tid];
            #pragma unroll
            for (int j = 0; j < 8; ++j) s[j] += (float)v[j];
        }
        #pragma unroll
        for (int j = 0; j < 8; ++j) red[kgs * 112 + c8 * 8 + j] = s[j];
    }
    __syncthreads();
    if (tid < CC) {
        float r = outb[tid];
        #pragma unroll
        for (int k = 0; k < 16; ++k) r += red[k * 112 + tid];
        out[b * CC + tid] = r;
    }
}

extern "C" void kernel_launch(void* const* d_in, const int* in_sizes, int n_in,
                              void* d_out, int out_size, void* d_ws, size_t ws_size,
                              hipStream_t stream) {
    const float* x    = (const float*)d_in[0];
    const float* selW = (const float*)d_in[1];
    const float* selb = (const float*)d_in[2];
    const float* outW = (const float*)d_in[3];
    const float* outb = (const float*)d_in[4];
    float* out = (float*)d_out;

    // ws: fv bf16 [49152*256]          = 25,165,824 B
    //     Wt bf16 [8192*7168]          = 117,440,512 B  (offset 25,165,824)
    //     part16  [256][512][112] fp16 = 29,360,128 B   (offset 142,606,336)
    unsigned short* fv = (unsigned short*)d_ws;
    unsigned short* Wt = (unsigned short*)((char*)d_ws + 25165824);
    _Float16* part16 = (_Float16*)((char*)d_ws + 142606336);

    wt_kernel<<<NIT, 256, 0, stream>>>(outW, Wt);
    fv_kernel<<<dim3(384, 2), 256, 0, stream>>>(x, selW, selb, fv);
    main_gemm<<<KG, 256, 0, stream>>>(fv, Wt, part16);
    reduce_k<<<BB, 256, 0, stream>>>(part16, outb, out);
}

// Round 6
// 350.561 us; speedup vs baseline: 1.2018x; 1.2018x over previous
//
#include <hip/hip_runtime.h>
#include <hip/hip_bf16.h>

// Problem constants
#define BB 256          // batch
#define FF 128          // features
#define CC 100          // classes
#define KG 256          // split-K groups (k-blocks of main_gemm)
#define ITPB 32         // it-pairs per main_gemm block (KG*ITPB = 8192)
#define NMACRO 16       // macro-iterations per block (2 its each)

typedef short bf16x8 __attribute__((ext_vector_type(8)));
typedef float f32x4 __attribute__((ext_vector_type(4)));
typedef _Float16 f16x8 __attribute__((ext_vector_type(8)));

static __device__ inline unsigned short f2bf(float f) {
    unsigned u = __float_as_uint(f);
    u += 0x7fffu + ((u >> 16) & 1u);   // RNE
    return (unsigned short)(u >> 16);
}
static __device__ inline float bf2f(unsigned short h) {
    return __uint_as_float(((unsigned)h) << 16);
}
// packed f32x2 -> bf16x2 (RNE), low16 = a
static __device__ inline unsigned pk2(float a, float b) {
    __hip_bfloat162 h = __float22bfloat162_rn(float2{a, b});
    union { __hip_bfloat162 h2; unsigned u; } cv; cv.h2 = h;
    return cv.u;
}
// async global->LDS, 16 B per lane; lds base wave-uniform, dest = base + lane*16
static __device__ inline void gl_lds16(const float* g, float* l) {
    __builtin_amdgcn_global_load_lds(
        (const __attribute__((address_space(1))) void*)g,
        (__attribute__((address_space(3))) void*)l, 16, 0, 0);
}

// ---------------------------------------------------------------------------
// Kernel 1: fv[row][b] = sigmoid(x[b,:] . sel_W[row,:] + sel_b[row])  (bf16)
// row = it*6 + d  ->  fv[row*256 + b]
// ---------------------------------------------------------------------------
__global__ __launch_bounds__(256) void fv_kernel(
    const float* __restrict__ x, const float* __restrict__ selW,
    const float* __restrict__ selb, unsigned short* __restrict__ fvout)
{
    __shared__ unsigned short wt[128 * 136];
    __shared__ unsigned short xt[128 * 136];
    __shared__ float sb[128];

    const int tid = threadIdx.x;
    const int m0 = blockIdx.x * 128;
    const int n0 = blockIdx.y * 128;

    #pragma unroll 4
    for (int pass = 0; pass < 16; ++pass) {
        int idx = pass * 256 + tid;
        int r = idx >> 5, f4 = idx & 31;
        float4 v = *((const float4*)(selW + (size_t)(m0 + r) * FF) + f4);
        float4 vx = *((const float4*)(x + (size_t)(n0 + r) * FF) + f4);
        ushort4 h;
        h.x = f2bf(v.x); h.y = f2bf(v.y); h.z = f2bf(v.z); h.w = f2bf(v.w);
        *(ushort4*)(wt + r * 136 + f4 * 4) = h;
        ushort4 hx;
        hx.x = f2bf(vx.x); hx.y = f2bf(vx.y); hx.z = f2bf(vx.z); hx.w = f2bf(vx.w);
        *(ushort4*)(xt + r * 136 + f4 * 4) = hx;
    }
    if (tid < 128) sb[tid] = selb[m0 + tid];
    __syncthreads();

    const int w = tid >> 6, lane = tid & 63;
    const int q = lane >> 4, l15 = lane & 15;
    const int mq = w & 1, nq = w >> 1;

    f32x4 zero4 = {0.f, 0.f, 0.f, 0.f};
    f32x4 acc[4][4];
    #pragma unroll
    for (int i = 0; i < 4; ++i)
        #pragma unroll
        for (int j = 0; j < 4; ++j) acc[i][j] = zero4;

    #pragma unroll
    for (int ch = 0; ch < 4; ++ch) {
        bf16x8 a[4];
        #pragma unroll
        for (int ms = 0; ms < 4; ++ms)
            a[ms] = *(const bf16x8*)(wt + (mq * 64 + ms * 16 + l15) * 136 + ch * 32 + q * 8);
        #pragma unroll
        for (int ns = 0; ns < 4; ++ns) {
            bf16x8 bfr = *(const bf16x8*)(xt + (nq * 64 + ns * 16 + l15) * 136 + ch * 32 + q * 8);
            #pragma unroll
            for (int ms = 0; ms < 4; ++ms)
                acc[ms][ns] = __builtin_amdgcn_mfma_f32_16x16x32_bf16(a[ms], bfr, acc[ms][ns], 0, 0, 0);
        }
    }

    #pragma unroll
    for (int ms = 0; ms < 4; ++ms) {
        int rowl = mq * 64 + ms * 16 + q * 4;
        #pragma unroll
        for (int ns = 0; ns < 4; ++ns) {
            int b = n0 + nq * 64 + ns * 16 + l15;
            #pragma unroll
            for (int reg = 0; reg < 4; ++reg) {
                int row = m0 + rowl + reg;
                float z = acc[ms][ns][reg] + sb[rowl + reg];
                float p = 1.0f / (1.0f + __expf(-z));
                fvout[(size_t)row * 256 + b] = f2bf(p);
            }
        }
    }
}

// ---------------------------------------------------------------------------
// Kernel 2: split-K x split-C GEMM with deep async pipeline.
// grid (KG, 2): kg = K-group (32 its), cg = c-half (56 classes).
// Per macro (2 its = K 128): stage 64 c-rows x 512 B of outW fp32 into LDS via
// global_load_lds (contiguous 512-B segments), double-buffered, distance-2.
// Per-row slot rotation s=r&7 applied at the global source for LDS bank spread.
// A-frags built in-register from shfl'd probabilities; B-frags = 2x ds_read_b128
// + pack to bf16. vmcnt never drains below the in-flight next group (20 vmem).
// ---------------------------------------------------------------------------
__global__ __launch_bounds__(256, 2) void main_gemm(
    const unsigned short* __restrict__ fv, const float* __restrict__ outW,
    _Float16* __restrict__ part16)
{
    __shared__ float buf[2][8192];   // 2 x 64 rows x 128 floats = 65536 B

    const int tid = threadIdx.x;
    const int kg = blockIdx.x;
    const int cg = blockIdx.y;
    const int w = tid >> 6, lane = tid & 63;
    const int q = lane >> 4, l15 = lane & 15;
    const int qh = q >> 1, ql = q & 1;
    const int cmax = cg ? 43 : 55;          // clamp row for async source
    const int half = lane >> 5;

    f32x4 zero4 = {0.f, 0.f, 0.f, 0.f};
    f32x4 acc[4][4];
    #pragma unroll
    for (int i = 0; i < 4; ++i)
        #pragma unroll
        for (int j = 0; j < 4; ++j) acc[i][j] = zero4;

    const unsigned short* fvp = fv + tid;
    unsigned short fvh[2][12];

    // ---- issue group for macro mm into buffer nb: 8 asyncs + 12 fv = 20 vmem
    #define ISSUE_GROUP(mm, nb)                                                  \
    {                                                                            \
        const size_t g0 = (size_t)kg * 2048 + (size_t)(mm) * 128;                \
        _Pragma("unroll")                                                        \
        for (int j = 0; j < 8; ++j) {                                            \
            const int rbase = w * 16 + 2 * j;                                    \
            const int r = rbase + half;                                          \
            const int s = r & 7;                                                 \
            const int slot = ((lane & 31) + s) & 31;                             \
            const int rc = r > cmax ? cmax : r;                                  \
            const int c = cg * 56 + rc;                                          \
            gl_lds16(outW + (size_t)c * 524288 + g0 + slot * 4,                  \
                     &buf[nb][rbase * 128]);                                     \
        }                                                                        \
        const int it0 = kg * ITPB + (mm) * 2;                                    \
        _Pragma("unroll")                                                        \
        for (int e = 0; e < 12; ++e)                                             \
            fvh[nb][e] = fvp[((size_t)(it0 + (e >= 6 ? 1 : 0)) * 6 + (e % 6)) * 256]; \
    }

    // prologue: macros 0 and 1 in flight
    ISSUE_GROUP(0, 0);
    ISSUE_GROUP(1, 1);

    #pragma unroll 2
    for (int m = 0; m < NMACRO; ++m) {
        const int cur = m & 1;

        // group(m) done (its 20 vmem are older than the newest 20 = group(m+1));
        // then all-waves barrier -> buf[cur] fully staged.
        asm volatile("s_waitcnt vmcnt(20)\n\ts_barrier" ::: "memory");

        // ---- B-fragments: 16 frags (4 k-chunks x 4 nt) from rotated stage ----
        bf16x8 bfr[4][4];
        #pragma unroll
        for (int ch = 0; ch < 4; ++ch) {
            #pragma unroll
            for (int nt = 0; nt < 4; ++nt) {
                const int r = nt * 16 + l15;
                const int s = r & 7;
                const int sl0 = ((ch * 8 + q * 2) - s) & 31;
                const int sl1 = ((ch * 8 + q * 2 + 1) - s) & 31;
                f32x4 lo = *(const f32x4*)&buf[cur][r * 128 + sl0 * 4];
                f32x4 hi = *(const f32x4*)&buf[cur][r * 128 + sl1 * 4];
                union { bf16x8 v; unsigned u[4]; } bu;
                bu.u[0] = pk2(lo[0], lo[1]);
                bu.u[1] = pk2(lo[2], lo[3]);
                bu.u[2] = pk2(hi[0], hi[1]);
                bu.u[3] = pk2(hi[2], hi[3]);
                bfr[ch][nt] = bu.v;
            }
        }

        // ---- per it: A-frags via shfl, then MFMA ----
        #pragma unroll
        for (int itl = 0; itl < 2; ++itl) {
            float p0 = bf2f(fvh[cur][itl * 6 + 0]);
            float p1 = bf2f(fvh[cur][itl * 6 + 1]);
            float p2 = bf2f(fvh[cur][itl * 6 + 2]);
            float p3 = bf2f(fvh[cur][itl * 6 + 3]);
            float p4 = bf2f(fvh[cur][itl * 6 + 4]);
            float p5 = bf2f(fvh[cur][itl * 6 + 5]);

            bf16x8 afr[4][2];
            #pragma unroll
            for (int ms = 0; ms < 4; ++ms) {
                const int src = ms * 16 + l15;
                float s0 = __shfl(p0, src, 64);
                float s1 = __shfl(p1, src, 64);
                float s2 = __shfl(p2, src, 64);
                float s3 = __shfl(p3, src, 64);
                float s4 = __shfl(p4, src, 64);
                float s5 = __shfl(p5, src, 64);
                float t1 = qh ? (1.f - s1) : s1;
                float A0 = s0 * t1;
                float A1 = (1.f - s0) * t1;
                float t2 = ql ? (1.f - s2) : s2;
                float Bv0 = t2 * s3;
                float Bv1 = t2 * (1.f - s3);
                float n4 = 1.f - s4, n5 = 1.f - s5;
                float Cv0 = s4 * s5, Cv1 = s4 * n5, Cv2 = n4 * s5, Cv3 = n4 * n5;
                #pragma unroll
                for (int chl = 0; chl < 2; ++chl) {
                    float A = chl ? A1 : A0;
                    float ab0 = A * Bv0, ab1 = A * Bv1;
                    union { bf16x8 v; unsigned u[4]; } bu;
                    bu.u[0] = pk2(ab0 * Cv0, ab0 * Cv1);
                    bu.u[1] = pk2(ab0 * Cv2, ab0 * Cv3);
                    bu.u[2] = pk2(ab1 * Cv0, ab1 * Cv1);
                    bu.u[3] = pk2(ab1 * Cv2, ab1 * Cv3);
                    afr[ms][chl] = bu.v;
                }
            }
            #pragma unroll
            for (int chl = 0; chl < 2; ++chl) {
                const int ch = itl * 2 + chl;
                #pragma unroll
                for (int nt = 0; nt < 4; ++nt)
                    #pragma unroll
                    for (int ms = 0; ms < 4; ++ms)
                        acc[ms][nt] = __builtin_amdgcn_mfma_f32_16x16x32_bf16(
                            afr[ms][chl], bfr[ch][nt], acc[ms][nt], 0, 0, 0);
            }
        }

        // all waves done reading buf[cur] (lgkm only; vmem stays in flight)
        asm volatile("s_waitcnt lgkmcnt(0)\n\ts_barrier" ::: "memory");

        // refill buf[cur] with macro m+2 (clamped re-issue keeps vmcnt count)
        const int mn = (m + 2 < NMACRO) ? (m + 2) : m;
        ISSUE_GROUP(mn, cur);
    }

    // epilogue: part16[b][kg][c], only real c columns for this cg
    const int slotmax = cg ? 44 : 56;
    #pragma unroll
    for (int ms = 0; ms < 4; ++ms) {
        const int brow = w * 64 + ms * 16 + q * 4;
        #pragma unroll
        for (int nt = 0; nt < 4; ++nt) {
            const int slot = nt * 16 + l15;
            if (slot < slotmax) {
                const int c = cg * 56 + slot;
                #pragma unroll
                for (int reg = 0; reg < 4; ++reg)
                    part16[((size_t)(brow + reg) * KG + kg) * 112 + c] =
                        (_Float16)acc[ms][nt][reg];
            }
        }
    }
    #undef ISSUE_GROUP
}

// ---------------------------------------------------------------------------
// Kernel 3: out[b][c] = sum_kg part16[b][kg][c] + out_b[c]
// One block per b; slice = 256*112 halves = 57344 B contiguous.
// ---------------------------------------------------------------------------
__global__ __launch_bounds__(256) void reduce_k(
    const _Float16* __restrict__ part16, const float* __restrict__ outb,
    float* __restrict__ out)
{
    __shared__ float red[16 * 112];
    const int b = blockIdx.x;
    const int tid = threadIdx.x;
    const f16x8* slice = (const f16x8*)(part16 + (size_t)b * (KG * 112));

    if (tid < 224) {
        const int c8 = tid % 14;       // c base = c8*8
        const int kgs = tid / 14;      // 0..15
        float s[8];
        #pragma unroll
        for (int j = 0; j < 8; ++j) s[j] = 0.f;
        #pragma unroll 4
        for (int i = 0; i < 16; ++i) { // kg = i*16 + kgs
            f16x8 v = slice[i * 224 + tid];
            #pragma unroll
            for (int j = 0; j < 8; ++j) s[j] += (float)v[j];
        }
        #pragma unroll
        for (int j = 0; j < 8; ++j) red[kgs * 112 + c8 * 8 + j] = s[j];
    }
    __syncthreads();
    if (tid < CC) {
        float r = outb[tid];
        #pragma unroll
        for (int k = 0; k < 16; ++k) r += red[k * 112 + tid];
        out[b * CC + tid] = r;
    }
}

extern "C" void kernel_launch(void* const* d_in, const int* in_sizes, int n_in,
                              void* d_out, int out_size, void* d_ws, size_t ws_size,
                              hipStream_t stream) {
    const float* x    = (const float*)d_in[0];
    const float* selW = (const float*)d_in[1];
    const float* selb = (const float*)d_in[2];
    const float* outW = (const float*)d_in[3];
    const float* outb = (const float*)d_in[4];
    float* out = (float*)d_out;

    // ws: fv bf16 [49152*256]          = 25,165,824 B
    //     part16  [256][256][112] fp16 = 14,680,064 B   (offset 25,165,824)
    unsigned short* fv = (unsigned short*)d_ws;
    _Float16* part16 = (_Float16*)((char*)d_ws + 25165824);

    fv_kernel<<<dim3(384, 2), 256, 0, stream>>>(x, selW, selb, fv);
    main_gemm<<<dim3(KG, 2), 256, 0, stream>>>(fv, outW, part16);
    reduce_k<<<BB, 256, 0, stream>>>(part16, outb, out);
}